// Round 11
// baseline (109.062 us; speedup 1.0000x reference)
//
#include <hip/hip_runtime.h>
#include <math.h>

// Fused: out[b,oc,y,x] = max_{dy,dx} min(xmax[b,y+dy-2,x+dx-2], k[oc,dy,dx])
// xmax = channel-max over C=32; OOB = -inf.
// x (16,32,256,256) f32, k (32,5,5) f32, out (16,32,256,256) f32.
//
// Block = TWO stacked 32x16 tiles (T0,T1), 1024 blocks (4/CU, all resident).
// Pipeline: phase1(T0) | lgkm-barrier | { per oc o: issue T1-load chunk o+1,
// fold chunk o, conv T0 oc o } | lgkm-barrier | conv(T1).
// vmcnt FIFO order guarantees load-waits never drain stores:
//   queue at fold(o) = [loads(o), stores(o-1), loads(o+1)] -> counted wait.
// Raw lgkm-only barriers avoid vmcnt(0) store drains at block syncs.

#define BATCH 16
#define CH    32
#define OCH   32
#define HH    256
#define WW    256
#define HWSZ  (HH * WW)
#define LH    20              // 16 + 4 halo rows per tile
#define LW    42              // 40 data cols + 2 pad (8B-aligned rows)
#define NWG   (BATCH * (HH / 32) * (WW / 32))   // 1024

typedef float floatx4 __attribute__((ext_vector_type(4)));

__device__ __forceinline__ float vmax3(float a, float b, float c) {
    float d;
    asm("v_max3_f32 %0, %1, %2, %3" : "=v"(d) : "v"(a), "v"(b), "v"(c));
    return d;
}

// Raw barrier: drain LDS ops only; leave global stores in flight.
__device__ __forceinline__ void lgkm_barrier() {
    asm volatile("s_waitcnt lgkmcnt(0)" ::: "memory");
    __builtin_amdgcn_s_barrier();
}

// conv for one oc: 2 rows x 4 px from the 6x8 register window, nt-stores.
__device__ __forceinline__ void conv_oc(const float (&w)[6][8], const float* __restrict__ kk,
                                        int oc, float* __restrict__ out, size_t obq) {
    const float* kw = kk + oc * 25;       // wave-uniform -> s_load (SGPR taps)
    float kr[25];
#pragma unroll
    for (int i = 0; i < 25; ++i) kr[i] = kw[i];
#pragma unroll
    for (int r = 0; r < 2; ++r) {
        float a[4];
#pragma unroll
        for (int j = 0; j < 4; ++j) {
            float mm[25];
#pragma unroll
            for (int dy = 0; dy < 5; ++dy)
#pragma unroll
                for (int dx = 0; dx < 5; ++dx)
                    mm[dy * 5 + dx] = fminf(w[r + dy][j + dx], kr[dy * 5 + dx]);
            float t0 = vmax3(mm[0],  mm[1],  mm[2]);
            float t1 = vmax3(mm[3],  mm[4],  mm[5]);
            float t2 = vmax3(mm[6],  mm[7],  mm[8]);
            float t3 = vmax3(mm[9],  mm[10], mm[11]);
            float t4 = vmax3(mm[12], mm[13], mm[14]);
            float t5 = vmax3(mm[15], mm[16], mm[17]);
            float t6 = vmax3(mm[18], mm[19], mm[20]);
            float t7 = vmax3(mm[21], mm[22], mm[23]);
            a[j] = vmax3(vmax3(t0, t1, t2), vmax3(t3, t4, t5), vmax3(t6, t7, mm[24]));
        }
        floatx4 ov = { a[0], a[1], a[2], a[3] };
        __builtin_nontemporal_store(ov, (floatx4*)(out + obq + (size_t)r * WW));
    }
}

__global__ __launch_bounds__(256, 4) void fused_maxmin_kernel(const float* __restrict__ x,
                                                              const float* __restrict__ kk,
                                                              float* __restrict__ out) {
    __shared__ float xmt[2][LH][LW];
    int tid = threadIdx.x;
    int bid = blockIdx.x;
    int swz = (bid & 7) * (NWG >> 3) + (bid >> 3);   // XCD-chunked, bijective (1024%8==0)
    int b   = swz >> 6;
    int t2  = swz & 63;
    int ty2 = t2 >> 3;                               // 0..7: output rows ty2*32..+31
    int tx  = t2 & 7;

    const float NI = -INFINITY;

    // phase1 granule coords (tid < 200): 20 rows x 10 float4 granules
    int pr = tid / 10, pc = tid % 10;
    int c4 = tx * 8 - 1 + pc;
    bool cvalid = (c4 >= 0) && (c4 < WW / 4);
    int c4c = c4 < 0 ? 0 : (c4 > WW / 4 - 1 ? WW / 4 - 1 : c4);
    const float4* xb4 = (const float4*)x + (size_t)b * CH * (HWSZ / 4);
    bool act = tid < 200;

    // ---- phase1(T0): halo rows ty2*32-2 .. +17 ----
    if (act) {
        int rw = ty2 * 32 - 2 + pr;
        bool valid = cvalid && (rw >= 0) && (rw < HH);
        int rwc = rw < 0 ? 0 : (rw > HH - 1 ? HH - 1 : rw);
        const float4* src = xb4 + (size_t)rwc * (WW / 4) + c4c;
        float4 m = src[0];
#pragma unroll
        for (int c = 1; c < CH; ++c) {
            float4 v = src[(size_t)c * (HWSZ / 4)];
            m.x = fmaxf(m.x, v.x); m.y = fmaxf(m.y, v.y);
            m.z = fmaxf(m.z, v.z); m.w = fmaxf(m.w, v.w);
        }
        if (!valid) { m.x = NI; m.y = NI; m.z = NI; m.w = NI; }
        *(float2*)&xmt[0][pr][4 * pc]     = make_float2(m.x, m.y);
        *(float2*)&xmt[0][pr][4 * pc + 2] = make_float2(m.z, m.w);
    }
    lgkm_barrier();

    // phase2 thread mapping: 4 px x 2 rows x 8 oc
    int xg = tid & 7;
    int rg = (tid >> 3) & 7;
    int wv = __builtin_amdgcn_readfirstlane(tid >> 6);

    // T1 phase1 source (halo rows ty2*32+14 .. +33; >=14 so no low clamp)
    int rw1 = ty2 * 32 + 14 + pr;
    bool valid1 = cvalid && (rw1 < HH);
    int rwc1 = rw1 > HH - 1 ? HH - 1 : rw1;
    const float4* src1 = xb4 + (size_t)rwc1 * (WW / 4) + c4c;

    // Prologue: issue T1-load chunk 0 (channels 0..3) before anything else.
    float4 v[2][4];
    if (act) {
#pragma unroll
        for (int j = 0; j < 4; ++j) v[0][j] = src1[(size_t)j * (HWSZ / 4)];
    }

    // T0 window: LDS rows 2rg..2rg+5, cols 4xg+2..4xg+9
    float w[6][8];
#pragma unroll
    for (int r = 0; r < 6; ++r) {
        const float* rp = &xmt[0][2 * rg + r][4 * xg + 2];
#pragma unroll
        for (int s = 0; s < 4; ++s)
            *(float2*)&w[r][2 * s] = *(const float2*)(rp + 2 * s);
    }

    size_t ob0 = (size_t)(b * OCH + wv * 8) * HWSZ
               + (size_t)(ty2 * 32 + 2 * rg) * WW + tx * 32 + 4 * xg;

    // ---- interleave: issue chunk o+1 -> fold chunk o -> conv T0 oc o ----
    float4 macc = make_float4(NI, NI, NI, NI);
#pragma unroll
    for (int o = 0; o < 8; ++o) {
        if (o < 7 && act) {
#pragma unroll
            for (int j = 0; j < 4; ++j)
                v[(o + 1) & 1][j] = src1[(size_t)(4 * (o + 1) + j) * (HWSZ / 4)];
        }
        if (act) {
            const float4* c = v[o & 1];
            macc.x = fmaxf(macc.x, fmaxf(fmaxf(c[0].x, c[1].x), fmaxf(c[2].x, c[3].x)));
            macc.y = fmaxf(macc.y, fmaxf(fmaxf(c[0].y, c[1].y), fmaxf(c[2].y, c[3].y)));
            macc.z = fmaxf(macc.z, fmaxf(fmaxf(c[0].z, c[1].z), fmaxf(c[2].z, c[3].z)));
            macc.w = fmaxf(macc.w, fmaxf(fmaxf(c[0].w, c[1].w), fmaxf(c[2].w, c[3].w)));
        }
        conv_oc(w, kk, wv * 8 + o, out, ob0 + (size_t)o * HWSZ);
    }
    if (act) {
        if (!valid1) { macc.x = NI; macc.y = NI; macc.z = NI; macc.w = NI; }
        *(float2*)&xmt[1][pr][4 * pc]     = make_float2(macc.x, macc.y);
        *(float2*)&xmt[1][pr][4 * pc + 2] = make_float2(macc.z, macc.w);
    }
    lgkm_barrier();

    // ---- phase2(T1) ----
#pragma unroll
    for (int r = 0; r < 6; ++r) {
        const float* rp = &xmt[1][2 * rg + r][4 * xg + 2];
#pragma unroll
        for (int s = 0; s < 4; ++s)
            *(float2*)&w[r][2 * s] = *(const float2*)(rp + 2 * s);
    }
    size_t ob1 = ob0 + (size_t)16 * WW;
    for (int o = 0; o < 8; ++o)
        conv_oc(w, kk, wv * 8 + o, out, ob1 + (size_t)o * HWSZ);
}

extern "C" void kernel_launch(void* const* d_in, const int* in_sizes, int n_in,
                              void* d_out, int out_size, void* d_ws, size_t ws_size,
                              hipStream_t stream) {
    const float* x  = (const float*)d_in[0];
    const float* kk = (const float*)d_in[1];
    float* out      = (float*)d_out;
    fused_maxmin_kernel<<<NWG, 256, 0, stream>>>(x, kk, out);
}

// Round 12
// 55.268 us; speedup vs baseline: 1.9733x; 1.9733x over previous
//
#include <hip/hip_runtime.h>
#include <math.h>

// Fused: out[b,oc,y,x] = max_{dy,dx} min(xmax[b,y+dy-2,x+dx-2], k[oc,dy,dx])
// xmax = channel-max over C=32; OOB = -inf.
// x (16,32,256,256) f32, k (32,5,5) f32, out (16,32,256,256) f32.
//
// Round-8 structure (best: 55.4us) + ONE change: all 32x25 taps staged to
// LDS once per block; per-oc taps read as 6x ds_read_b128 + ds_read_b32 at
// wave-uniform addresses (broadcast) instead of 200 global v-loads/thread
// (round-8 SGPR_Count=32 proved the compiler never emitted s_load for taps).

#define BATCH 16
#define CH    32
#define OCH   32
#define HH    256
#define WW    256
#define HWSZ  (HH * WW)
#define TW    32
#define TH    16
#define LH    20              // TH + 4
#define LW    42              // stride: 40 data cols + 2 pad; rows 8B-aligned
#define KP    28              // padded tap row (floats): 112 B, 16B-aligned
#define NWG   (BATCH * (HH / TH) * (WW / TW))   // 2048

typedef float floatx4 __attribute__((ext_vector_type(4)));

__device__ __forceinline__ float vmax3(float a, float b, float c) {
    float d;
    asm("v_max3_f32 %0, %1, %2, %3" : "=v"(d) : "v"(a), "v"(b), "v"(c));
    return d;
}

__global__ __launch_bounds__(256, 2) void fused_maxmin_kernel(const float* __restrict__ x,
                                                              const float* __restrict__ kk,
                                                              float* __restrict__ out) {
    __shared__ float xmt[LH][LW];
    __shared__ float lk[OCH * KP];     // padded taps: oc*28 base -> 16B-aligned
    int tid = threadIdx.x;
    int bid = blockIdx.x;
    int swz = (bid & 7) * (NWG >> 3) + (bid >> 3);   // XCD-chunked, bijective (2048%8==0)
    int b   = swz >> 7;                              // 128 tiles/batch
    int t2  = swz & 127;
    int ty  = t2 >> 3;                               // 0..15
    int tx  = t2 & 7;                                // 0..7

    const float NI = -INFINITY;

    // ---- tap staging: 800 floats, coalesced ----
    for (int i = tid; i < OCH * 25; i += 256)
        lk[(i / 25) * KP + (i % 25)] = kk[i];

    // ---- Phase 1: channel max of 20 rows x 10 float4 granules ----
    if (tid < 200) {
        int pr = tid / 10;                           // LDS row 0..19
        int pc = tid % 10;                           // granule 0..9
        int c4 = tx * 8 - 1 + pc;                    // global float4 col
        int rw = ty * TH - 2 + pr;                   // global row
        bool valid = (c4 >= 0) && (c4 < WW / 4) && (rw >= 0) && (rw < HH);
        int c4c = c4 < 0 ? 0 : (c4 > WW / 4 - 1 ? WW / 4 - 1 : c4);
        int rwc = rw < 0 ? 0 : (rw > HH - 1 ? HH - 1 : rw);
        const float4* src = (const float4*)x + (size_t)b * CH * (HWSZ / 4)
                          + (size_t)rwc * (WW / 4) + c4c;
        float4 m = src[0];
#pragma unroll
        for (int c = 1; c < CH; ++c) {
            float4 v = src[(size_t)c * (HWSZ / 4)];
            m.x = fmaxf(m.x, v.x);
            m.y = fmaxf(m.y, v.y);
            m.z = fmaxf(m.z, v.z);
            m.w = fmaxf(m.w, v.w);
        }
        if (!valid) { m.x = NI; m.y = NI; m.z = NI; m.w = NI; }
        *(float2*)&xmt[pr][4 * pc]     = make_float2(m.x, m.y);   // stride 42 -> 8B align
        *(float2*)&xmt[pr][4 * pc + 2] = make_float2(m.z, m.w);
    }
    __syncthreads();

    // ---- Phase 2 ----
    int xg = tid & 7;                                // 8 groups x 4 px
    int rg = (tid >> 3) & 7;                         // 8 groups x 2 rows
    int wv = __builtin_amdgcn_readfirstlane(tid >> 6);   // wave -> oc 8*wv..8*wv+7

    // Window: LDS rows 2rg..2rg+5, cols 4xg+2..4xg+9 (8B-aligned float2 reads).
    float w[6][8];
#pragma unroll
    for (int r = 0; r < 6; ++r) {
        const float* rp = &xmt[2 * rg + r][4 * xg + 2];
#pragma unroll
        for (int s = 0; s < 4; ++s)
            *(float2*)&w[r][2 * s] = *(const float2*)(rp + 2 * s);
    }

    size_t obase = (size_t)(b * OCH + wv * 8) * HWSZ
                 + (size_t)(ty * TH + 2 * rg) * WW + tx * TW + 4 * xg;

    for (int o = 0; o < 8; ++o) {
        // taps via 6x ds_read_b128 + ds_read_b32, wave-uniform -> broadcast
        const float* kv = &lk[(wv * 8 + o) * KP];
        float4 q0 = *(const float4*)(kv + 0);
        float4 q1 = *(const float4*)(kv + 4);
        float4 q2 = *(const float4*)(kv + 8);
        float4 q3 = *(const float4*)(kv + 12);
        float4 q4 = *(const float4*)(kv + 16);
        float4 q5 = *(const float4*)(kv + 20);
        float  k24 = kv[24];
        float kr[25] = { q0.x,q0.y,q0.z,q0.w, q1.x,q1.y,q1.z,q1.w,
                         q2.x,q2.y,q2.z,q2.w, q3.x,q3.y,q3.z,q3.w,
                         q4.x,q4.y,q4.z,q4.w, q5.x,q5.y,q5.z,q5.w, k24 };

        float* op = out + obase + (size_t)o * HWSZ;
#pragma unroll
        for (int r = 0; r < 2; ++r) {
            float a[4];
#pragma unroll
            for (int j = 0; j < 4; ++j) {
                float m[25];
#pragma unroll
                for (int dy = 0; dy < 5; ++dy)
#pragma unroll
                    for (int dx = 0; dx < 5; ++dx)
                        m[dy * 5 + dx] = fminf(w[r + dy][j + dx], kr[dy * 5 + dx]);
                float t0 = vmax3(m[0],  m[1],  m[2]);
                float t1 = vmax3(m[3],  m[4],  m[5]);
                float t2 = vmax3(m[6],  m[7],  m[8]);
                float t3 = vmax3(m[9],  m[10], m[11]);
                float t4 = vmax3(m[12], m[13], m[14]);
                float t5 = vmax3(m[15], m[16], m[17]);
                float t6 = vmax3(m[18], m[19], m[20]);
                float t7 = vmax3(m[21], m[22], m[23]);
                float u0 = vmax3(t0, t1, t2);
                float u1 = vmax3(t3, t4, t5);
                float u2 = vmax3(t6, t7, m[24]);
                a[j] = vmax3(u0, u1, u2);
            }
            floatx4 ov = { a[0], a[1], a[2], a[3] };
            __builtin_nontemporal_store(ov, (floatx4*)(op + (size_t)r * WW));
        }
    }
}

extern "C" void kernel_launch(void* const* d_in, const int* in_sizes, int n_in,
                              void* d_out, int out_size, void* d_ws, size_t ws_size,
                              hipStream_t stream) {
    const float* x  = (const float*)d_in[0];
    const float* kk = (const float*)d_in[1];
    float* out      = (float*)d_out;
    fused_maxmin_kernel<<<NWG, 256, 0, stream>>>(x, kk, out);
}